// Round 10
// baseline (214.004 us; speedup 1.0000x reference)
//
#include <hip/hip_runtime.h>
#include <hip/hip_bf16.h>

// B=4, S=2048, D=1024, DH=64. Inputs/outputs are FLOAT32 (per reference).
// Staged operands (xh/xl, wth/wtl, t1, sg) use 64-col PANEL layout:
//   elem = ((panel)*ROWS + row)*64 + col  -> 128x64 tile = contiguous 16KB DMA
typedef short bf16x8 __attribute__((ext_vector_type(8)));
typedef float f32x4  __attribute__((ext_vector_type(4)));
typedef _Float16 f16x8 __attribute__((ext_vector_type(8)));

#define MFMA16(a,b,c)  __builtin_amdgcn_mfma_f32_16x16x32_bf16((a),(b),(c),0,0,0)
#define MFMAF16(a,b,c) __builtin_amdgcn_mfma_f32_16x16x32_f16((a),(b),(c),0,0,0)

#define GLDS16(g,l) __builtin_amdgcn_global_load_lds( \
    (const __attribute__((address_space(1))) void*)(g), \
    (__attribute__((address_space(3))) void*)(l), 16, 0, 0)

// p3 bins: 136 tri-tiles LPT-packed into 128 bins (2 blocks/CU); cnt<=2
struct P3Bins { unsigned char cnt[128]; unsigned char tiles[128][4]; };

__device__ __forceinline__ short f2bf(float f){
  union { float f; unsigned u; } v; v.f = f;
  unsigned r = v.u + 0x7fffu + ((v.u >> 16) & 1u);
  return (short)(r >> 16);
}
__device__ __forceinline__ float bf2f(short h){
  union { unsigned u; float f; } v; v.u = ((unsigned)(unsigned short)h) << 16;
  return v.f;
}
__device__ __forceinline__ void split8v(f32x4 a, f32x4 b, bf16x8& h, bf16x8& l){
  float t[8] = {a[0],a[1],a[2],a[3],b[0],b[1],b[2],b[3]};
  #pragma unroll
  for (int e = 0; e < 8; ++e){
    short hs = f2bf(t[e]);
    h[e] = hs;
    l[e] = f2bf(t[e] - bf2f(hs));
  }
}

// ---------------- P0a: weights -> panel layout [p][kp][n][64] bf16 hi/lo ----------------
__global__ void k_wt(const float* w0, const float* w1, const float* w2,
                     const float* w3, const float* w4, const float* w5,
                     unsigned short* __restrict__ wth, unsigned short* __restrict__ wtl){
  int p = blockIdx.y;
  const float* wp = p==0?w0:p==1?w1:p==2?w2:p==3?w3:p==4?w4:w5;
  int idx = blockIdx.x*256 + threadIdx.x;     // [0,65536)
  int n = idx >> 10, k = idx & 1023;
  float v = wp[k*64 + n];
  short hs = f2bf(v);
  size_t d = (size_t)p*65536 + (size_t)(k>>6)*4096 + n*64 + (k&63);
  wth[d] = (unsigned short)hs;
  wtl[d] = (unsigned short)f2bf(v - bf2f(hs));
}

// ---------------- P0b: x f32 -> xh/xl bf16 panels [kp][s][64] ----------------
__global__ void k_xsplit(const float* __restrict__ x,
                         unsigned short* __restrict__ xh, unsigned short* __restrict__ xl){
  size_t i = ((size_t)blockIdx.x*256 + threadIdx.x)*8;
  int s = (int)(i >> 10), k = (int)(i & 1023);
  f32x4 a = *(const f32x4*)(x + i);
  f32x4 b = *(const f32x4*)(x + i + 4);
  bf16x8 h, l;
  split8v(a, b, h, l);
  size_t d = (size_t)(k>>6)*524288 + (size_t)s*64 + (k&63);
  *(bf16x8*)(xh + d) = h;
  *(bf16x8*)(xl + d) = l;
}

// ---------------- P1: projections, 2 p's per block, panel-DMA staged ----------------
__global__ __launch_bounds__(256) void k_proj(
    const unsigned short* __restrict__ xh, const unsigned short* __restrict__ xl,
    const unsigned short* __restrict__ wth, const unsigned short* __restrict__ wtl,
    float* __restrict__ proj,
    unsigned short* __restrict__ projh, unsigned short* __restrict__ projl){
  __shared__ __align__(16) char sm[49152];  // xh 8K | xl 8K | w0h 8K | w0l 8K | w1h 8K | w1l 8K
  int blk = blockIdx.x;
  int rb = blk/3, pg = blk - rb*3;
  int tid = threadIdx.x, w = tid >> 6, lane = tid & 63;
  int lm = lane & 15, quad = lane >> 4;
  int srow = lane >> 3, scg = (lane & 7) ^ srow;
  const char* xhg = (const char*)xh;
  const char* xlg = (const char*)xl;
  const char* w0h = (const char*)wth + (size_t)(pg*2  )*131072;
  const char* w0l = (const char*)wtl + (size_t)(pg*2  )*131072;
  const char* w1h = (const char*)wth + (size_t)(pg*2+1)*131072;
  const char* w1l = (const char*)wtl + (size_t)(pg*2+1)*131072;
  f32x4 acc[2][4] = {};
  for (int k0 = 0; k0 < 1024; k0 += 64){
    int kp = k0 >> 6;
    __syncthreads();
    #pragma unroll
    for (int i2 = 0; i2 < 2; ++i2){
      int i = w*2 + i2;
      int rl = i*8 + srow;
      size_t gx = (size_t)kp*1048576 + (size_t)(rb*64 + rl)*128 + scg*16;
      size_t gw = (size_t)kp*8192 + (size_t)rl*128 + scg*16;
      GLDS16(xhg + gx, sm +         i*1024);
      GLDS16(xlg + gx, sm +  8192 + i*1024);
      GLDS16(w0h + gw, sm + 16384 + i*1024);
      GLDS16(w0l + gw, sm + 24576 + i*1024);
      GLDS16(w1h + gw, sm + 32768 + i*1024);
      GLDS16(w1l + gw, sm + 40960 + i*1024);
    }
    __syncthreads();
    #pragma unroll
    for (int ks = 0; ks < 2; ++ks){
      int ra = w*16 + lm;
      int offa = ra*128 + (((ks*4+quad) ^ (ra&7))*16);
      bf16x8 ah = *(const bf16x8*)(sm + offa);
      bf16x8 al = *(const bf16x8*)(sm + 8192 + offa);
      #pragma unroll
      for (int sub = 0; sub < 2; ++sub){
        #pragma unroll
        for (int n = 0; n < 4; ++n){
          int r = n*16 + lm;
          int off = r*128 + (((ks*4+quad) ^ (r&7))*16);
          bf16x8 bh = *(const bf16x8*)(sm + 16384 + sub*16384 + off);
          bf16x8 bl = *(const bf16x8*)(sm + 24576 + sub*16384 + off);
          acc[sub][n] = MFMA16(ah, bh, acc[sub][n]);
          acc[sub][n] = MFMA16(ah, bl, acc[sub][n]);
          acc[sub][n] = MFMA16(al, bh, acc[sub][n]);
        }
      }
    }
  }
  #pragma unroll
  for (int sub = 0; sub < 2; ++sub){
    int p = pg*2 + sub;
    if (p == 5){
      float* op = proj + (size_t)5*524288;
      #pragma unroll
      for (int n = 0; n < 4; ++n)
        #pragma unroll
        for (int e = 0; e < 4; ++e){
          int r = rb*64 + w*16 + quad*4 + e;
          op[(size_t)r*64 + n*16 + lm] = acc[sub][n][e];
        }
    } else {
      unsigned short* oph = projh + (size_t)p*524288;
      unsigned short* opl = projl + (size_t)p*524288;
      #pragma unroll
      for (int n = 0; n < 4; ++n)
        #pragma unroll
        for (int e = 0; e < 4; ++e){
          int r = rb*64 + w*16 + quad*4 + e;
          float f = acc[sub][n][e];
          short hs = f2bf(f);
          oph[(size_t)r*64 + n*16 + lm] = (unsigned short)hs;
          opl[(size_t)r*64 + n*16 + lm] = (unsigned short)f2bf(f - bf2f(hs));
        }
    }
  }
}

// ---------------- P1b: V_c f32 -> V_c^T fp16 (per batch 64 x 2048) ----------------
__global__ void k_vct(const float* __restrict__ proj, _Float16* __restrict__ vct){
  __shared__ float T[64][65];
  int b = blockIdx.y, st = blockIdx.x;       // s-tile [0,32)
  int tid = threadIdx.x;
  const float* vc = proj + 5*524288 + (size_t)b*131072;
  int sloc = tid >> 2, cp = (tid & 3)*16;
  #pragma unroll
  for (int j = 0; j < 4; ++j){
    f32x4 v = *(const f32x4*)(vc + (size_t)(st*64 + sloc)*64 + cp + j*4);
    #pragma unroll
    for (int e = 0; e < 4; ++e) T[sloc][cp + j*4 + e] = v[e];
  }
  __syncthreads();
  int d = tid >> 2, sp = (tid & 3)*16;
  f16x8 h0, h1;
  #pragma unroll
  for (int j = 0; j < 8; ++j) h0[j] = (_Float16)T[sp + j][d];
  #pragma unroll
  for (int j = 0; j < 8; ++j) h1[j] = (_Float16)T[sp + 8 + j][d];
  size_t o = (size_t)b*131072 + (size_t)d*2048 + st*64 + sp;
  *(f16x8*)(vct + o) = h0; *(f16x8*)(vct + o + 8) = h1;
}

// ---------------- P2: term1/sig tiles -> fp16 PANELS [b][j64][s][64] ----------------
__global__ __launch_bounds__(256,2) void k_p2(
    const unsigned short* __restrict__ ph, const unsigned short* __restrict__ pl,
    _Float16* __restrict__ t1, _Float16* __restrict__ sg){
  __shared__ __align__(16) char sm[65536];
  int b = blockIdx.y;
  int t = blockIdx.x;                        // [0,272): 136 term1 + 136 sig tiles
  bool isSig = t >= 136;
  if (isSig) t -= 136;
  int a = 0, bb = 0;
  #pragma unroll 1
  for (int aa = 0; aa < 16; ++aa){
    int c = isSig ? (16 - aa) : (aa + 1);
    if (t < c){ a = aa; bb = isSig ? (aa + t) : t; break; }
    t -= c;
  }
  int pa = isSig ? 0 : 3;                    // A = Qu : Qc
  int pb = isSig ? 1 : 2;                    // B = Ku : Vu
  const char* Ahg = (const char*)ph + (size_t)pa*1048576;
  const char* Alg = (const char*)pl + (size_t)pa*1048576;
  const char* Bhg = (const char*)ph + (size_t)pb*1048576;
  const char* Blg = (const char*)pl + (size_t)pb*1048576;
  int tid = threadIdx.x, w = tid >> 6, lane = tid & 63;
  int lm = lane & 15, quad = lane >> 4;
  int srow = lane >> 3, scg = (lane & 7) ^ srow;
  int wm = (w & 1)*64, wn = (w >> 1)*64;
  #pragma unroll
  for (int i2 = 0; i2 < 4; ++i2){
    int i = w*4 + i2;
    int rl = i*8 + srow;
    size_t ga = (size_t)(b*2048 + a*128  + rl)*128 + scg*16;
    size_t gb = (size_t)(b*2048 + bb*128 + rl)*128 + scg*16;
    GLDS16(Ahg + ga, sm +         i*1024);
    GLDS16(Alg + ga, sm + 16384 + i*1024);
    GLDS16(Bhg + gb, sm + 32768 + i*1024);
    GLDS16(Blg + gb, sm + 49152 + i*1024);
  }
  __syncthreads();
  f32x4 acc[4][4] = {};
  #pragma unroll
  for (int ks = 0; ks < 2; ++ks){
    bf16x8 bh[4], bl[4];
    #pragma unroll
    for (int n = 0; n < 4; ++n){
      int r = wn + n*16 + lm;
      int off = r*128 + (((ks*4+quad) ^ (r&7))*16);
      bh[n] = *(const bf16x8*)(sm + 32768 + off);
      bl[n] = *(const bf16x8*)(sm + 49152 + off);
    }
    #pragma unroll
    for (int m = 0; m < 4; ++m){
      int r = wm + m*16 + lm;
      int off = r*128 + (((ks*4+quad) ^ (r&7))*16);
      bf16x8 ah = *(const bf16x8*)(sm + off);
      bf16x8 al = *(const bf16x8*)(sm + 16384 + off);
      #pragma unroll
      for (int n = 0; n < 4; ++n){
        acc[m][n] = MFMA16(ah, bh[n], acc[m][n]);
        acc[m][n] = MFMA16(ah, bl[n], acc[m][n]);
        acc[m][n] = MFMA16(al, bh[n], acc[m][n]);
      }
    }
  }
  __syncthreads();
  _Float16* Tt = (_Float16*)sm;              // 128x128 fp16 tile
  #pragma unroll
  for (int m = 0; m < 4; ++m){
    #pragma unroll
    for (int n = 0; n < 4; ++n){
      #pragma unroll
      for (int e = 0; e < 4; ++e){
        int il = wm + m*16 + quad*4 + e;
        int jl = wn + n*16 + lm;
        int gi = a*128 + il, gj = bb*128 + jl;
        float v = acc[m][n][e] * 0.125f;
        float outv;
        if (!isSig) outv = (gj <= gi) ? v : 0.0f;
        else        outv = (gj >  gi) ? (1.0f/(1.0f + __expf(-v))) : 0.0f;
        Tt[il*128 + jl] = (_Float16)outv;
      }
    }
  }
  __syncthreads();
  char* outp = (char*)(isSig ? sg : t1);
  #pragma unroll
  for (int r = 0; r < 8; ++r){
    int lrow = w*32 + r*4 + (lane >> 4);
    int c16 = lane & 15;
    int jp = 2*bb + (c16 >> 3);              // panel index
    f32x4 vv = *(const f32x4*)(sm + lrow*256 + c16*16);
    size_t d = ((size_t)(b*32 + jp)*2048 + a*128 + lrow)*128 + (c16 & 7)*16;
    *(f32x4*)(outp + d) = vv;
  }
}

// ---------------- P3: S_u (fp16 MFMA, dbuf, panel-DMA) + S_c, 128 LPT bins ----------------
__global__ __launch_bounds__(256,2) void k_p3(
    const unsigned short* __restrict__ ph, const unsigned short* __restrict__ pl,
    const _Float16* __restrict__ t1, const _Float16* __restrict__ sg,
    _Float16* __restrict__ lg, P3Bins bz){
  __shared__ __align__(16) char sm[65536];   // buf0: A@0 B@16K | buf1: A@32K B@48K
  int bin = blockIdx.x;
  int b = blockIdx.y;
  int tid = threadIdx.x, w = tid >> 6, lane = tid & 63;
  int lm = lane & 15, quad = lane >> 4;
  const char* Ag = (const char*)t1;
  const char* Bg = (const char*)sg;
  int srow = lane >> 3, scg = (lane & 7) ^ srow;
  int wm = (w & 1)*64, wn = (w >> 1)*64;
  int ntiles = bz.cnt[bin];

  for (int tix = 0; tix < ntiles; ++tix){
    int tv = bz.tiles[bin][tix];
    int I = tv >> 4, K = tv & 15;
    int nsteps = 2*(I - K) + 2;
    int j0 = 2*K;
    __syncthreads();                          // LDS reuse vs previous tile epilogue

    auto stage = [&](int j64, int base){
      size_t pbase = (size_t)(b*32 + j64)*2048;
      #pragma unroll
      for (int i2 = 0; i2 < 4; ++i2){
        int i = w*4 + i2;
        int rl = i*8 + srow;
        GLDS16(Ag + (pbase + I*128 + rl)*128 + scg*16, sm + base +         i*1024);
        GLDS16(Bg + (pbase + K*128 + rl)*128 + scg*16, sm + base + 16384 + i*1024);
      }
    };

    f32x4 su[4][4] = {};
    stage(j0, 0);
    for (int step = 0; step < nsteps; ++step){
      int cur = (step & 1) << 15;
      __syncthreads();                        // drains cur's DMA
      if (step + 1 < nsteps) stage(j0 + step + 1, (~step & 1) << 15);
      #pragma unroll
      for (int ks = 0; ks < 2; ++ks){
        f16x8 bf[4];
        #pragma unroll
        for (int n = 0; n < 4; ++n){
          int r = wn + n*16 + lm;
          bf[n] = *(const f16x8*)(sm + cur + 16384 + r*128 + (((ks*4+quad) ^ (r&7))*16));
        }
        #pragma unroll
        for (int m = 0; m < 4; ++m){
          int r = wm + m*16 + lm;
          f16x8 af = *(const f16x8*)(sm + cur + r*128 + (((ks*4+quad) ^ (r&7))*16));
          #pragma unroll
          for (int n = 0; n < 4; ++n)
            su[m][n] = MFMAF16(af, bf[n], su[m][n]);
        }
      }
    }
    // fused S_c = Qc @ Kc^T (split bf16 from prebuilt h/l)
    const char* Qh = (const char*)ph + (size_t)3*1048576;
    const char* Ql = (const char*)pl + (size_t)3*1048576;
    const char* Kh = (const char*)ph + (size_t)4*1048576;
    const char* Kl = (const char*)pl + (size_t)4*1048576;
    f32x4 sc[4][4] = {};
    #pragma unroll
    for (int ks = 0; ks < 2; ++ks){
      bf16x8 kh[4], kl[4];
      #pragma unroll
      for (int n = 0; n < 4; ++n){
        size_t off = (size_t)(b*2048 + K*128 + wn + n*16 + lm)*128 + (ks*32 + quad*8)*2;
        kh[n] = *(const bf16x8*)(Kh + off);
        kl[n] = *(const bf16x8*)(Kl + off);
      }
      #pragma unroll
      for (int m = 0; m < 4; ++m){
        size_t off = (size_t)(b*2048 + I*128 + wm + m*16 + lm)*128 + (ks*32 + quad*8)*2;
        bf16x8 ah = *(const bf16x8*)(Qh + off);
        bf16x8 al = *(const bf16x8*)(Ql + off);
        #pragma unroll
        for (int n = 0; n < 4; ++n){
          sc[m][n] = MFMA16(ah, kh[n], sc[m][n]);
          sc[m][n] = MFMA16(ah, kl[n], sc[m][n]);
          sc[m][n] = MFMA16(al, kh[n], sc[m][n]);
        }
      }
    }
    __syncthreads();
    _Float16* Tt = (_Float16*)sm;            // 128x128 fp16 logits tile
    #pragma unroll
    for (int m = 0; m < 4; ++m){
      #pragma unroll
      for (int n = 0; n < 4; ++n){
        #pragma unroll
        for (int e = 0; e < 4; ++e){
          int il = wm + m*16 + quad*4 + e;
          int jl = wn + n*16 + lm;
          float xv = su[m][n][e];
          float sgm = 1.0f/(1.0f + __expf(-xv));
          Tt[il*128 + jl] = (_Float16)(sc[m][n][e]*0.125f - xv*sgm);
        }
      }
    }
    __syncthreads();
    _Float16* lgb = lg + (size_t)b*4194304;  // lg stays row-major (p4 reads rows)
    #pragma unroll
    for (int r = 0; r < 8; ++r){
      int lrow = w*32 + r*4 + (lane >> 4);
      int c16 = lane & 15;
      f32x4 vv = *(const f32x4*)(sm + lrow*256 + c16*16);
      *(f32x4*)((char*)(lgb + (size_t)(I*128 + lrow)*2048 + K*128) + c16*16) = vv;
    }
  }
}

// ---------------- P4 (fused): band softmax + P @ V_c, paired bands ----------------
__global__ __launch_bounds__(256,2) void k_p4(const _Float16* __restrict__ lg,
    const _Float16* __restrict__ vct, float* __restrict__ out){
  __shared__ __align__(16) char sm[66048];   // Ls 64K | Mz 256B | Sz 256B
  float* Mz = (float*)(sm + 65536);
  float* Sz = (float*)(sm + 65792);
  int b = blockIdx.y;
  int b1 = blockIdx.x;                       // handles bands b1 and 127-b1
  int tid = threadIdx.x, w = tid >> 6, lane = tid & 63;
  int lm = lane & 15, quad = lane >> 4;
  const _Float16* vb = vct + (size_t)b*131072;
  for (int pass = 0; pass < 2; ++pass){
    int band = pass ? (127 - b1) : b1;
    int r0 = band*16;
    const char* lgb = (const char*)lg + ((size_t)b*4194304 + (size_t)r0*2048)*2;
    int nkt = ((r0 + 15) >> 6) + 1;
    int fc = (r0 + 1) >> 6;
    int srl = lane >> 3, ssl = lane & 7;
    __syncthreads();
    for (int kt = w; kt < nkt; kt += 4){
      #pragma unroll
      for (int i2 = 0; i2 < 2; ++i2){
        int rl = i2*8 + srl;
        GLDS16(lgb + (size_t)rl*4096 + kt*128 + ((ssl ^ (rl & 7))*16),
               sm + kt*2048 + i2*1024);
      }
    }
    __syncthreads();
    float m_r = -3.0e38f;
    for (int kt = w; kt < nkt; kt += 4){
      #pragma unroll
      for (int half = 0; half < 2; ++half){
        int sl = quad*2 + half;
        f16x8 v = *(const f16x8*)(sm + kt*2048 + lm*128 + ((sl ^ (lm & 7))*16));
        int cb = kt*64 + sl*8;
        #pragma unroll
        for (int e = 0; e < 8; ++e)
          m_r = (cb + e <= r0 + lm) ? fmaxf(m_r, (float)v[e]) : m_r;
      }
    }
    m_r = fmaxf(m_r, __shfl_xor(m_r, 16));
    m_r = fmaxf(m_r, __shfl_xor(m_r, 32));
    Mz[w*16 + lm] = m_r;
    __syncthreads();
    float mfin = fmaxf(fmaxf(Mz[lm], Mz[16 + lm]), fmaxf(Mz[32 + lm], Mz[48 + lm]));
    float s_r = 0.0f;
    for (int kt = w; kt < nkt; kt += 4){
      #pragma unroll
      for (int half = 0; half < 2; ++half){
        int sl = quad*2 + half;
        f16x8 v = *(const f16x8*)(sm + kt*2048 + lm*128 + ((sl ^ (lm & 7))*16));
        int cb = kt*64 + sl*8;
        #pragma unroll
        for (int e = 0; e < 8; ++e)
          if (cb + e <= r0 + lm) s_r += __expf((float)v[e] - mfin);
      }
    }
    s_r += __shfl_xor(s_r, 16);
    s_r += __shfl_xor(s_r, 32);
    Sz[w*16 + lm] = s_r;
    f32x4 acc[4] = {};
    for (int kt = w; kt < nkt; kt += 4){
      bool full = kt < fc;
      #pragma unroll
      for (int ks = 0; ks < 2; ++ks){
        f16x8 Lv = *(const f16x8*)(sm + kt*2048 + lm*128 + (((ks*4+quad) ^ (lm & 7))*16));
        int jbase = kt*64 + ks*32 + quad*8;
        f16x8 af;
        #pragma unroll
        for (int e = 0; e < 8; ++e){
          float p = __expf((float)Lv[e] - mfin);
          if (!full && (jbase + e > r0 + lm)) p = 0.0f;
          af[e] = (_Float16)p;
        }
        #pragma unroll
        for (int n = 0; n < 4; ++n){
          f16x8 bv = *(const f16x8*)(vb + (size_t)(n*16 + lm)*2048 + jbase);
          acc[n] = MFMAF16(af, bv, acc[n]);
        }
      }
    }
    __syncthreads();
    float* Ot = (float*)sm;
    #pragma unroll
    for (int n = 0; n < 4; ++n)
      #pragma unroll
      for (int e = 0; e < 4; ++e)
        Ot[(w*16 + quad*4 + e)*64 + n*16 + lm] = acc[n][e];
    __syncthreads();
    int row = tid >> 4, c4 = (tid & 15)*4;
    f32x4 s = *(const f32x4*)&Ot[row*64 + c4];
    #pragma unroll
    for (int ww = 1; ww < 4; ++ww){
      f32x4 t2 = *(const f32x4*)&Ot[(ww*16 + row)*64 + c4];
      s[0]+=t2[0]; s[1]+=t2[1]; s[2]+=t2[2]; s[3]+=t2[3];
    }
    float z = Sz[row] + Sz[16 + row] + Sz[32 + row] + Sz[48 + row];
    f32x4 o = { s[0]/z, s[1]/z, s[2]/z, s[3]/z };
    *(f32x4*)(out + ((size_t)b*2048 + r0 + row)*64 + c4) = o;
  }
}

// ---------------- workspace layout (bytes) ----------------
static const size_t OFF_PROJ  = 0;           // 8192x64 f32 (p5 only used)
static const size_t OFF_WTH   = 12582912;    // 6 x 64x1024 bf16 (panels)
static const size_t OFF_WTL   = 13369344;
static const size_t OFF_PROJH = 14155776;    // 6 x 8192x64 bf16
static const size_t OFF_PROJL = 20447232;
static const size_t OFF_VCT   = 26738688;    // 4 x 64x2048 f16
static const size_t OFF_T1    = 27787264;    // 4 x 2048^2 f16 (panels)
static const size_t OFF_SG    = 61341696;
static const size_t OFF_LG    = 94896128;    // row-major
static const size_t OFF_XH    = 128450560;   // 8192x1024 bf16 (panels)
static const size_t OFF_XL    = 145227776;
// total = 162,004,992 bytes

static P3Bins build_bins(){
  P3Bins bz;
  int load[128];
  for (int i = 0; i < 128; ++i){ bz.cnt[i] = 0; load[i] = 0; }
  for (int d = 15; d >= 0; --d){
    for (int K = 0; K + d < 16; ++K){
      int I = K + d;
      int len = 2*d + 2;
      int best = 0;
      for (int bin = 1; bin < 128; ++bin) if (load[bin] < load[best]) best = bin;
      load[best] += len;
      bz.tiles[best][bz.cnt[best]++] = (unsigned char)(I*16 + K);
    }
  }
  return bz;
}

extern "C" void kernel_launch(void* const* d_in, const int* in_sizes, int n_in,
                              void* d_out, int out_size, void* d_ws, size_t ws_size,
                              hipStream_t stream){
  (void)in_sizes; (void)n_in; (void)out_size; (void)ws_size;
  const float* x = (const float*)d_in[0];
  char* ws = (char*)d_ws;
  float*          proj  = (float*)(ws + OFF_PROJ);
  unsigned short* wth   = (unsigned short*)(ws + OFF_WTH);
  unsigned short* wtl   = (unsigned short*)(ws + OFF_WTL);
  unsigned short* projh = (unsigned short*)(ws + OFF_PROJH);
  unsigned short* projl = (unsigned short*)(ws + OFF_PROJL);
  _Float16*       vct   = (_Float16*)(ws + OFF_VCT);
  _Float16*       t1    = (_Float16*)(ws + OFF_T1);
  _Float16*       sg    = (_Float16*)(ws + OFF_SG);
  _Float16*       lg    = (_Float16*)(ws + OFF_LG);
  unsigned short* xh    = (unsigned short*)(ws + OFF_XH);
  unsigned short* xl    = (unsigned short*)(ws + OFF_XL);

  P3Bins bz = build_bins();

  k_wt    <<<dim3(256,6),  256, 0, stream>>>((const float*)d_in[1], (const float*)d_in[2],
                                             (const float*)d_in[3], (const float*)d_in[4],
                                             (const float*)d_in[5], (const float*)d_in[6], wth, wtl);
  k_xsplit<<<dim3(4096),   256, 0, stream>>>(x, xh, xl);
  k_proj  <<<dim3(384),    256, 0, stream>>>(xh, xl, wth, wtl, proj, projh, projl);
  k_vct   <<<dim3(32,4),   256, 0, stream>>>(proj, vct);
  k_p2    <<<dim3(272,4),  256, 0, stream>>>(projh, projl, t1, sg);
  k_p3    <<<dim3(128,4),  256, 0, stream>>>(projh, projl, t1, sg, lg, bz);
  k_p4    <<<dim3(64,4),   256, 0, stream>>>(lg, vct, (float*)d_out);
}